// Round 16
// baseline (54.987 us; speedup 1.0000x reference)
//
#include <hip/hip_runtime.h>
#include <hip/hip_bf16.h>

// ---------------- constants ----------------
#define B_SZ 2
#define L_SZ 512
#define D_MODEL 512
#define D_INNER 1024
#define HEAD_DIM 64
#define NHEADS 16
#define D_STATE 64
#define D_CONV 3
#define CONV_DIM 1152            // D_INNER + 2*D_STATE
#define D_IN_PROJ 2192           // 2*D_INNER + 2*D_STATE + NHEADS
#define BL (B_SZ * L_SZ)         // 1024
#define RMS_EPS 1e-5f
#define QC 64                    // SSD chunk length
#define NCH 8                    // chunks per batch
#define NPAD1 2304               // W_in^T padded rows
#define PB 72                    // bf16 LDS pitch

typedef __attribute__((ext_vector_type(8))) short short8t;
typedef __attribute__((ext_vector_type(8))) unsigned short ushort8t;
typedef __attribute__((ext_vector_type(4))) unsigned short ushort4t;
typedef __attribute__((ext_vector_type(4))) float f32x4;

__device__ __forceinline__ unsigned short f2bf(float f) {
    unsigned u = __float_as_uint(f);
    u += 0x7fff + ((u >> 16) & 1);          // RNE
    return (unsigned short)(u >> 16);
}
__device__ __forceinline__ float bf2f(unsigned short u) {
    return __uint_as_float(((unsigned)u) << 16);
}

__device__ __forceinline__ void gload_lds16(const void* g, void* lds) {
    __builtin_amdgcn_global_load_lds(
        (const __attribute__((address_space(1))) unsigned int*)g,
        (__attribute__((address_space(3))) unsigned int*)lds, 16, 0, 0);
}

// ---------------- prep: W transposes (+rms fold) + u -> bf16 + flag reset ----------------
__device__ __forceinline__ void transpose_tile_bf16(const float* __restrict__ src,
                                                    const float* __restrict__ scale,
                                                    unsigned short* __restrict__ dst,
                                                    int K, int Nin, int tile, int ntn) {
    __shared__ float T[64][65];
    int tid = threadIdx.x;
    int nt = tile % ntn, kt = tile / ntn;
    int n0 = nt * 64, k0 = kt * 64;
#pragma unroll
    for (int rr = 0; rr < 4; ++rr) {
        int k = k0 + (tid >> 4) + rr * 16;
        float sc = scale ? scale[k] : 1.f;
        int nn = (tid & 15) * 4;
#pragma unroll
        for (int q = 0; q < 4; ++q) {
            int n = n0 + nn + q;
            T[(tid >> 4) + rr * 16][nn + q] = (n < Nin) ? src[(size_t)k * Nin + n] * sc : 0.f;
        }
    }
    __syncthreads();
    int nn2 = tid >> 2, kc = tid & 3;
    unsigned short ov[16];
#pragma unroll
    for (int j = 0; j < 16; ++j) ov[j] = f2bf(T[kc * 16 + j][nn2]);
    unsigned short* p = dst + (size_t)(n0 + nn2) * K + k0 + kc * 16;
    *(ushort8t*)p = *(ushort8t*)&ov[0];
    *(ushort8t*)(p + 8) = *(ushort8t*)&ov[8];
}

__global__ __launch_bounds__(256) void prep_kernel(const float* __restrict__ W_in,
                                                   const float* __restrict__ W_out,
                                                   const float* __restrict__ rms_w,
                                                   const float* __restrict__ u,
                                                   unsigned short* __restrict__ Wt1,
                                                   unsigned short* __restrict__ Wt2,
                                                   unsigned short* __restrict__ u_bf,
                                                   unsigned* __restrict__ flags) {
    int bid = blockIdx.x;
    if (bid == 0) flags[threadIdx.x] = 0u;   // 256 chunk-flags
    if (bid < 288) {
        transpose_tile_bf16(W_in, nullptr, Wt1, D_MODEL, D_IN_PROJ, bid, 36);
    } else if (bid < 416) {
        transpose_tile_bf16(W_out, rms_w, Wt2, D_INNER, D_MODEL, bid - 288, 8);
    } else {
        int i = ((bid - 416) * 256 + threadIdx.x) * 8;
        float4 v0 = *(const float4*)(u + i);
        float4 v1 = *(const float4*)(u + i + 4);
        unsigned short ov[8] = {f2bf(v0.x), f2bf(v0.y), f2bf(v0.z), f2bf(v0.w),
                                f2bf(v1.x), f2bf(v1.y), f2bf(v1.z), f2bf(v1.w)};
        *(ushort8t*)(u_bf + i) = *(ushort8t*)&ov[0];
    }
}

// ---------------- in_proj GEMM 64x64 + split epilogue (bf16 outputs) ----------------
__global__ __launch_bounds__(256) void gemm_in(const unsigned short* __restrict__ A,
                                               const unsigned short* __restrict__ Bt,
                                               unsigned short* __restrict__ z_bf,
                                               unsigned short* __restrict__ xbc,
                                               float* __restrict__ dtb) {
    const int K = D_MODEL;
    __shared__ char sm[49152];
    int tid = threadIdx.x;
    int w = tid >> 6, l = tid & 63;
    int m0 = blockIdx.y * 64, n0 = blockIdx.x * 64;
    int wm = w >> 1, wn = w & 1;

    f32x4 acc[2][2];
#pragma unroll
    for (int i = 0; i < 2; ++i)
#pragma unroll
        for (int j = 0; j < 2; ++j) acc[i][j] = (f32x4){0.f, 0.f, 0.f, 0.f};

    auto stage = [&](const unsigned short* src, int row0, int k0, char* dst) {
#pragma unroll
        for (int p = 0; p < 2; ++p) {
            int c = w * 2 + p;
            int row = c * 8 + (l >> 3);
            int scb = ((l & 7) << 4) ^ ((row & 7) << 4);
            gload_lds16(src + (size_t)(row0 + row) * K + k0 + (scb >> 1), dst + c * 1024);
        }
    };

    const int nkt = K / 64;   // 8
    stage(A, m0, 0, sm);
    stage(Bt, n0, 0, sm + 8192);
    stage(A, m0, 64, sm + 16384);
    stage(Bt, n0, 64, sm + 16384 + 8192);

    for (int kt = 0; kt < nkt; ++kt) {
        if (kt + 2 < nkt) {
            char* d = sm + ((kt + 2) % 3) * 16384;
            stage(A, m0, (kt + 2) * 64, d);
            stage(Bt, n0, (kt + 2) * 64, d + 8192);
        }
        int inflight = nkt - 1 - kt;
        if (inflight >= 2)      asm volatile("s_waitcnt vmcnt(8)" ::: "memory");
        else if (inflight == 1) asm volatile("s_waitcnt vmcnt(4)" ::: "memory");
        else                    asm volatile("s_waitcnt vmcnt(0)" ::: "memory");
        __builtin_amdgcn_s_barrier();

        const char* Ab = sm + (kt % 3) * 16384;
        const char* Bb = Ab + 8192;
#pragma unroll
        for (int kk = 0; kk < 2; ++kk) {
            short8t af[2], bf[2];
#pragma unroll
            for (int i = 0; i < 2; ++i) {
                int r = wm * 32 + i * 16 + (l & 15);
                int cb = (kk * 64 + (l >> 4) * 16) ^ ((r & 7) << 4);
                af[i] = *(const short8t*)(Ab + r * 128 + cb);
            }
#pragma unroll
            for (int j = 0; j < 2; ++j) {
                int r = wn * 32 + j * 16 + (l & 15);
                int cb = (kk * 64 + (l >> 4) * 16) ^ ((r & 7) << 4);
                bf[j] = *(const short8t*)(Bb + r * 128 + cb);
            }
#pragma unroll
            for (int i = 0; i < 2; ++i)
#pragma unroll
                for (int j = 0; j < 2; ++j)
                    acc[i][j] = __builtin_amdgcn_mfma_f32_16x16x32_bf16(af[i], bf[j], acc[i][j], 0, 0, 0);
        }
        __builtin_amdgcn_s_barrier();
    }

#pragma unroll
    for (int i = 0; i < 2; ++i)
#pragma unroll
        for (int j = 0; j < 2; ++j) {
            int row = m0 + wm * 32 + i * 16 + (l >> 4) * 4;
            int col = n0 + wn * 32 + j * 16 + (l & 15);
#pragma unroll
            for (int r = 0; r < 4; ++r) {
                float v = acc[i][j][r];
                int rr = row + r;
                if (col < D_INNER) {
                    z_bf[(size_t)rr * D_INNER + col] = f2bf(v);
                } else if (col < D_INNER + CONV_DIM) {
                    xbc[(size_t)rr * CONV_DIM + (col - D_INNER)] = f2bf(v);
                } else if (col < D_IN_PROJ) {
                    dtb[(size_t)rr * 16 + (col - D_INNER - CONV_DIM)] = v;
                }
            }
        }
}

// conv+SiLU of 4 channels from compact bf16 xbc; gl = seq position (causal clamp)
__device__ __forceinline__ float4 conv4b(const unsigned short* __restrict__ xrow,
                                         int gl, int ch,
                                         const float* __restrict__ conv_w,
                                         const float* __restrict__ conv_b) {
    ushort4t u2 = *(const ushort4t*)(xrow + ch);
    ushort4t u1 = {0, 0, 0, 0}, u0 = {0, 0, 0, 0};
    if (gl >= 1) u1 = *(const ushort4t*)(xrow + ch - CONV_DIM);
    if (gl >= 2) u0 = *(const ushort4t*)(xrow + ch - 2 * CONV_DIM);
    float4 o;
    float a;
    a = conv_b[ch+0] + conv_w[(ch+0)*3]*bf2f(u0[0]) + conv_w[(ch+0)*3+1]*bf2f(u1[0]) + conv_w[(ch+0)*3+2]*bf2f(u2[0]);
    o.x = a / (1.f + __expf(-a));
    a = conv_b[ch+1] + conv_w[(ch+1)*3]*bf2f(u0[1]) + conv_w[(ch+1)*3+1]*bf2f(u1[1]) + conv_w[(ch+1)*3+2]*bf2f(u2[1]);
    o.y = a / (1.f + __expf(-a));
    a = conv_b[ch+2] + conv_w[(ch+2)*3]*bf2f(u0[2]) + conv_w[(ch+2)*3+1]*bf2f(u1[2]) + conv_w[(ch+2)*3+2]*bf2f(u2[2]);
    o.z = a / (1.f + __expf(-a));
    a = conv_b[ch+3] + conv_w[(ch+3)*3]*bf2f(u0[3]) + conv_w[(ch+3)*3+1]*bf2f(u1[3]) + conv_w[(ch+3)*3+2]*bf2f(u2[3]);
    o.w = a / (1.f + __expf(-a));
    return o;
}

__device__ __forceinline__ float silu(float z) { return z / (1.f + __expf(-z)); }

// ---------------- fused SSD: diag + inter-chunk via producer-consumer flags ----------------
// 256 blocks (b,c,h), all co-resident on 256 CUs; block publishes its Z then (c>0)
// waits for chunks j<c of same (b,h). DAG -> deadlock-free. r8 proved the
// RELEASE/ACQUIRE AGENT-scope pattern is correct cross-XCD on this chip.
__global__ __launch_bounds__(256) void ssd_fused(const unsigned short* __restrict__ xbc,
                                                 const float* __restrict__ dtb,
                                                 const unsigned short* __restrict__ z_bf,
                                                 const float* __restrict__ conv_w,
                                                 const float* __restrict__ conv_b,
                                                 const float* __restrict__ dt_bias,
                                                 const float* __restrict__ A_log,
                                                 const float* __restrict__ D_param,
                                                 unsigned short* __restrict__ yz_bf,
                                                 float* __restrict__ psum,
                                                 unsigned short* __restrict__ Zbuf,
                                                 float* __restrict__ dec,
                                                 unsigned* __restrict__ flags) {
    int blk = blockIdx.x;          // b*128 + c*16 + h
    int h = blk & 15;
    int c = (blk >> 4) & 7;
    int b = blk >> 7;
    int bh = b * NHEADS + h;
    int tid = threadIdx.x;

    __shared__ __align__(16) unsigned short Cs_bf[QC][PB];   // C[t][n] (kept for Y_off)
    __shared__ __align__(16) unsigned short Bs_bf[QC][PB];   // B[s][n] -> P[t][s] after G
    __shared__ __align__(16) unsigned short XDT_bf[QC][PB];  // XD^T[p][t^f8(p)]
    __shared__ __align__(16) unsigned short BTw_bf[QC][PB];  // (w·B)^T -> S_prev[p][n] later
    __shared__ float csh[QC], dts[QC], wh[QC];
    __shared__ float sq_lds[QC][2];
#define P_bf Bs_bf
#define S_bf BTw_bf

    int bl0 = b * L_SZ + c * QC;

    // phase 0: dt softplus + cumsum + decays (wave 0)
    if (tid < 64) {
        int t = tid;
        float draw = dtb[(size_t)(bl0 + t) * 16 + h];
        float dtv = draw + dt_bias[h];
        dtv = (dtv > 20.f) ? dtv : log1pf(expf(dtv));
        float A = -expf(A_log[h]);
        float cs = A * dtv;
#pragma unroll
        for (int off = 1; off < 64; off <<= 1) {
            float tmp = __shfl_up(cs, off);
            if (t >= off) cs += tmp;
        }
        float cs63 = __shfl(cs, 63);
        dts[t] = dtv;
        csh[t] = cs;
        wh[t] = __expf(cs63 - cs);
        if (t == 0) dec[bh * NCH + c] = __expf(cs63);
    }

    int row16 = tid >> 4;
    int col4 = (tid & 15) * 4;
    // phase 1: conv B, C
#pragma unroll
    for (int r = 0; r < 4; ++r) {
        int t = r * 16 + row16;
        int gl = c * QC + t;
        const unsigned short* xrow = xbc + (size_t)(bl0 + t) * CONV_DIM;
        float4 Bv = conv4b(xrow, gl, D_INNER + col4, conv_w, conv_b);
        float4 Cv = conv4b(xrow, gl, D_INNER + D_STATE + col4, conv_w, conv_b);
        ushort4t bq = {f2bf(Bv.x), f2bf(Bv.y), f2bf(Bv.z), f2bf(Bv.w)};
        ushort4t cq = {f2bf(Cv.x), f2bf(Cv.y), f2bf(Cv.z), f2bf(Cv.w)};
        *(ushort4t*)&Bs_bf[t][col4] = bq;
        *(ushort4t*)&Cs_bf[t][col4] = cq;
    }
    __syncthreads();               // sync1: Bs/Cs/dts/wh visible

    // phase 2: conv x -> XD^T (f8-swizzled); BTw (w folded)
#pragma unroll
    for (int r = 0; r < 4; ++r) {
        int t = r * 16 + row16;
        int gl = c * QC + t;
        const unsigned short* xrow = xbc + (size_t)(bl0 + t) * CONV_DIM;
        float4 xv = conv4b(xrow, gl, h * HEAD_DIM + col4, conv_w, conv_b);
        float d = dts[t], wt = wh[t];
        xv.x *= d; xv.y *= d; xv.z *= d; xv.w *= d;
        ushort4t xq = {f2bf(xv.x), f2bf(xv.y), f2bf(xv.z), f2bf(xv.w)};
        ushort4t bq = *(ushort4t*)&Bs_bf[t][col4];
#pragma unroll
        for (int q = 0; q < 4; ++q) {
            int ch = col4 + q;
            int f8 = ((ch >> 2) & 7) << 3;
            XDT_bf[ch][t ^ f8] = xq[q];
            BTw_bf[ch][t ^ f8] = f2bf(bf2f(bq[q]) * wt);
        }
    }
    __syncthreads();               // sync2: XDT/BTw visible

    int l = tid & 63, wv = tid >> 6;
    int wm = wv >> 1, wn = wv & 1;
    int fr = l & 15, fq = l >> 4;

    // phase 3: G = C·B^T
    f32x4 g[2][2];
#pragma unroll
    for (int i = 0; i < 2; ++i)
#pragma unroll
        for (int j = 0; j < 2; ++j) g[i][j] = (f32x4){0.f, 0.f, 0.f, 0.f};
#pragma unroll
    for (int kk = 0; kk < 2; ++kk) {
        short8t af[2], bb[2];
#pragma unroll
        for (int i = 0; i < 2; ++i)
            af[i] = *(const short8t*)&Cs_bf[wm * 32 + i * 16 + fr][kk * 32 + fq * 8];
#pragma unroll
        for (int j = 0; j < 2; ++j)
            bb[j] = *(const short8t*)&Bs_bf[wn * 32 + j * 16 + fr][kk * 32 + fq * 8];
#pragma unroll
        for (int i = 0; i < 2; ++i)
#pragma unroll
            for (int j = 0; j < 2; ++j)
                g[i][j] = __builtin_amdgcn_mfma_f32_16x16x32_bf16(af[i], bb[j], g[i][j], 0, 0, 0);
    }
    __syncthreads();               // sync3: Bs reads done -> P overwrites Bs

    // phase 4: mask+decay -> P (into Bs region; Cs preserved for Y_off)
#pragma unroll
    for (int i = 0; i < 2; ++i)
#pragma unroll
        for (int j = 0; j < 2; ++j) {
            int s = wn * 32 + j * 16 + fr;
            float css = csh[s];
#pragma unroll
            for (int r = 0; r < 4; ++r) {
                int t = wm * 32 + i * 16 + fq * 4 + r;
                float v = (s <= t) ? g[i][j][r] * __expf(csh[t] - css) : 0.f;
                P_bf[t][s] = f2bf(v);
            }
        }
    __syncthreads();               // sync4: P visible

    // phase 5: Y_diag = P·XD (kept in regs)
    f32x4 yv[2][2];
#pragma unroll
    for (int i = 0; i < 2; ++i)
#pragma unroll
        for (int j = 0; j < 2; ++j) yv[i][j] = (f32x4){0.f, 0.f, 0.f, 0.f};
#pragma unroll
    for (int kk = 0; kk < 2; ++kk) {
        short8t af[2], bb[2];
        int K0 = kk * 32 + fq * 8;
#pragma unroll
        for (int i = 0; i < 2; ++i)
            af[i] = *(const short8t*)&P_bf[wm * 32 + i * 16 + fr][K0];
#pragma unroll
        for (int j = 0; j < 2; ++j) {
            int r = wn * 32 + j * 16 + fr;
            bb[j] = *(const short8t*)&XDT_bf[r][K0 ^ (((r >> 2) & 7) << 3)];
        }
#pragma unroll
        for (int i = 0; i < 2; ++i)
#pragma unroll
            for (int j = 0; j < 2; ++j)
                yv[i][j] = __builtin_amdgcn_mfma_f32_16x16x32_bf16(af[i], bb[j], yv[i][j], 0, 0, 0);
    }

    // phase 6: Z = XD^T·(w·B) -> Zbuf (bf16), publish flag
    {
        f32x4 zv[2][2];
#pragma unroll
        for (int i = 0; i < 2; ++i)
#pragma unroll
            for (int j = 0; j < 2; ++j) zv[i][j] = (f32x4){0.f, 0.f, 0.f, 0.f};
#pragma unroll
        for (int kk = 0; kk < 2; ++kk) {
            short8t af[2], bb[2];
            int K0 = kk * 32 + fq * 8;
#pragma unroll
            for (int i = 0; i < 2; ++i) {
                int r = wm * 32 + i * 16 + fr;
                af[i] = *(const short8t*)&XDT_bf[r][K0 ^ (((r >> 2) & 7) << 3)];
            }
#pragma unroll
            for (int j = 0; j < 2; ++j) {
                int r = wn * 32 + j * 16 + fr;
                bb[j] = *(const short8t*)&BTw_bf[r][K0 ^ (((r >> 2) & 7) << 3)];
            }
#pragma unroll
            for (int i = 0; i < 2; ++i)
#pragma unroll
                for (int j = 0; j < 2; ++j)
                    zv[i][j] = __builtin_amdgcn_mfma_f32_16x16x32_bf16(af[i], bb[j], zv[i][j], 0, 0, 0);
        }
        unsigned short* Zr = Zbuf + (((size_t)bh * NCH) + c) * (HEAD_DIM * D_STATE);
#pragma unroll
        for (int i = 0; i < 2; ++i)
#pragma unroll
            for (int j = 0; j < 2; ++j) {
                int n = wn * 32 + j * 16 + fr;
#pragma unroll
                for (int r = 0; r < 4; ++r) {
                    int p = wm * 32 + i * 16 + fq * 4 + r;
                    Zr[p * D_STATE + n] = f2bf(zv[i][j][r]);
                }
            }
    }
    asm volatile("s_waitcnt vmcnt(0)" ::: "memory");   // this wave's Z (and dec) stores retired
    __syncthreads();                                    // all waves retired
    if (tid == 0)
        __hip_atomic_store(&flags[bh * NCH + c], 1u, __ATOMIC_RELEASE, __HIP_MEMORY_SCOPE_AGENT);

    // phase 7 (c>0): wait for earlier chunks, S_prev = sum_j wgt_j Z(j), Y_off += C·S^T
    if (c > 0) {
        if (tid == 0) {
            for (int j = 0; j < c; ++j)
                while (__hip_atomic_load(&flags[bh * NCH + j], __ATOMIC_ACQUIRE,
                                         __HIP_MEMORY_SCOPE_AGENT) == 0u)
                    __builtin_amdgcn_s_sleep(8);
        }
        __syncthreads();           // sync6: Z(j<c) visible (BTw reads also done)

        {   // S_prev -> S_bf (BTw region), plain layout [p][n]
            int p = tid >> 2, nq = (tid & 3) * 16;
            const unsigned short* Zb = Zbuf + ((size_t)bh * NCH) * (HEAD_DIM * D_STATE);
            float S16[16];
#pragma unroll
            for (int qq = 0; qq < 16; ++qq) S16[qq] = 0.f;
            float wgt = 1.f;
            for (int j = c - 1; j >= 0; --j) {
                const unsigned short* Zj = Zb + (size_t)j * (HEAD_DIM * D_STATE) + p * D_STATE + nq;
                ushort8t za = *(const ushort8t*)Zj;
                ushort8t zb2 = *(const ushort8t*)(Zj + 8);
#pragma unroll
                for (int qq = 0; qq < 8; ++qq) {
                    S16[qq] += wgt * bf2f(za[qq]);
                    S16[8 + qq] += wgt * bf2f(zb2[qq]);
                }
                wgt *= dec[bh * NCH + j];
            }
#pragma unroll
            for (int q4 = 0; q4 < 4; ++q4) {
                ushort4t s4 = {f2bf(S16[q4 * 4 + 0]), f2bf(S16[q4 * 4 + 1]),
                               f2bf(S16[q4 * 4 + 2]), f2bf(S16[q4 * 4 + 3])};
                *(ushort4t*)&S_bf[p][nq + q4 * 4] = s4;
            }
        }
        __syncthreads();           // sync7: S visible

        f32x4 acc[2][2];
#pragma unroll
        for (int i = 0; i < 2; ++i)
#pragma unroll
            for (int j = 0; j < 2; ++j) acc[i][j] = (f32x4){0.f, 0.f, 0.f, 0.f};
#pragma unroll
        for (int kk = 0; kk < 2; ++kk) {
            short8t af[2], bb[2];
#pragma unroll
            for (int i = 0; i < 2; ++i)
                af[i] = *(const short8t*)&Cs_bf[wm * 32 + i * 16 + fr][kk * 32 + fq * 8];
#pragma unroll
            for (int j = 0; j < 2; ++j)
                bb[j] = *(const short8t*)&S_bf[wn * 32 + j * 16 + fr][kk * 32 + fq * 8];
#pragma unroll
            for (int i = 0; i < 2; ++i)
#pragma unroll
                for (int j = 0; j < 2; ++j)
                    acc[i][j] = __builtin_amdgcn_mfma_f32_16x16x32_bf16(af[i], bb[j], acc[i][j], 0, 0, 0);
        }
#pragma unroll
        for (int i = 0; i < 2; ++i)
#pragma unroll
            for (int j = 0; j < 2; ++j)
#pragma unroll
                for (int r = 0; r < 4; ++r) {
                    int t = wm * 32 + i * 16 + fq * 4 + r;
                    yv[i][j][r] += __expf(csh[t]) * acc[i][j][r];
                }
    }

    // phase 8 (all c): + D·x, gate with SiLU(z), psum, yz_bf
    {
        float Dp = D_param[h];
        float sloc[2][4] = {{0.f, 0.f, 0.f, 0.f}, {0.f, 0.f, 0.f, 0.f}};
#pragma unroll
        for (int i = 0; i < 2; ++i)
#pragma unroll
            for (int j = 0; j < 2; ++j) {
                int p = wn * 32 + j * 16 + fr;
                int f8 = ((p >> 2) & 7) << 3;
#pragma unroll
                for (int r = 0; r < 4; ++r) {
                    int t = wm * 32 + i * 16 + fq * 4 + r;
                    float xval = bf2f(XDT_bf[p][t ^ f8]);
                    float yval = yv[i][j][r] + (Dp / dts[t]) * xval;
                    size_t idx = (size_t)(bl0 + t) * D_INNER + h * HEAD_DIM + p;
                    float z = bf2f(z_bf[idx]);
                    float yz = yval * silu(z);
                    yz_bf[idx] = f2bf(yz);
                    sloc[i][r] += yz * yz;
                }
            }
#pragma unroll
        for (int i = 0; i < 2; ++i)
#pragma unroll
            for (int r = 0; r < 4; ++r) {
                float v = sloc[i][r];
                v += __shfl_xor(v, 1); v += __shfl_xor(v, 2);
                v += __shfl_xor(v, 4); v += __shfl_xor(v, 8);
                if (fr == 0) {
                    int t = wm * 32 + i * 16 + fq * 4 + r;
                    sq_lds[t][wn] = v;
                }
            }
        __syncthreads();
        if (tid < 64)
            psum[(size_t)(bl0 + tid) * 16 + h] = sq_lds[tid][0] + sq_lds[tid][1];
    }
#undef P_bf
#undef S_bf
}

// ---------------- out_proj GEMM 32x64 + RMS row-scale epilogue ----------------
__global__ __launch_bounds__(256) void gemm_out(const unsigned short* __restrict__ A,
                                                const unsigned short* __restrict__ Bt,
                                                const float* __restrict__ psum,
                                                float* __restrict__ C) {
    const int N = D_MODEL, K = D_INNER;
    __shared__ char sm[36864];
    __shared__ float scl[32];
    int tid = threadIdx.x;
    int w = tid >> 6, l = tid & 63;
    int m0 = blockIdx.y * 32, n0 = blockIdx.x * 64;
    int wm = w >> 1, wn = w & 1;

    f32x4 acc[2];
    acc[0] = (f32x4){0.f, 0.f, 0.f, 0.f};
    acc[1] = (f32x4){0.f, 0.f, 0.f, 0.f};

    auto stageA = [&](int k0, char* dst) {
        int row = w * 8 + (l >> 3);
        int scb = ((l & 7) << 4) ^ ((row & 7) << 4);
        gload_lds16(A + (size_t)(m0 + row) * K + k0 + (scb >> 1), dst + w * 1024);
    };
    auto stageB = [&](int k0, char* dst) {
#pragma unroll
        for (int p = 0; p < 2; ++p) {
            int c = w * 2 + p;
            int row = c * 8 + (l >> 3);
            int scb = ((l & 7) << 4) ^ ((row & 7) << 4);
            gload_lds16(Bt + (size_t)(n0 + row) * K + k0 + (scb >> 1), dst + c * 1024);
        }
    };

    const int nkt = K / 64;   // 16
    stageA(0, sm); stageB(0, sm + 4096);
    stageA(64, sm + 12288); stageB(64, sm + 12288 + 4096);

    for (int kt = 0; kt < nkt; ++kt) {
        if (kt + 2 < nkt) {
            char* d = sm + ((kt + 2) % 3) * 12288;
            stageA((kt + 2) * 64, d);
            stageB((kt + 2) * 64, d + 4096);
        }
        int inflight = nkt - 1 - kt;
        if (inflight >= 2)      asm volatile("s_waitcnt vmcnt(6)" ::: "memory");
        else if (inflight == 1) asm volatile("s_waitcnt vmcnt(3)" ::: "memory");
        else                    asm volatile("s_waitcnt vmcnt(0)" ::: "memory");
        __builtin_amdgcn_s_barrier();

        const char* Ab = sm + (kt % 3) * 12288;
        const char* Bb = Ab + 4096;
#pragma unroll
        for (int kk = 0; kk < 2; ++kk) {
            short8t af;
            {
                int r = wm * 16 + (l & 15);
                int cb = (kk * 64 + (l >> 4) * 16) ^ ((r & 7) << 4);
                af = *(const short8t*)(Ab + r * 128 + cb);
            }
#pragma unroll
            for (int j = 0; j < 2; ++j) {
                int r = wn * 32 + j * 16 + (l & 15);
                int cb = (kk * 64 + (l >> 4) * 16) ^ ((r & 7) << 4);
                short8t bfv = *(const short8t*)(Bb + r * 128 + cb);
                acc[j] = __builtin_amdgcn_mfma_f32_16x16x32_bf16(af, bfv, acc[j], 0, 0, 0);
            }
        }
        __builtin_amdgcn_s_barrier();
    }

    if (tid < 32) {
        const float* pr = psum + (size_t)(m0 + tid) * 16;
        float s = 0.f;
#pragma unroll
        for (int qq = 0; qq < 16; ++qq) s += pr[qq];
        scl[tid] = rsqrtf(s / (float)D_INNER + RMS_EPS);
    }
    __syncthreads();

#pragma unroll
    for (int j = 0; j < 2; ++j) {
        int col = n0 + wn * 32 + j * 16 + (l & 15);
        int rloc = wm * 16 + (l >> 4) * 4;
#pragma unroll
        for (int r = 0; r < 4; ++r)
            C[(size_t)(m0 + rloc + r) * N + col] = acc[j][r] * scl[rloc + r];
    }
}

// ---------------- launch ----------------
extern "C" void kernel_launch(void* const* d_in, const int* in_sizes, int n_in,
                              void* d_out, int out_size, void* d_ws, size_t ws_size,
                              hipStream_t stream) {
    const float* u       = (const float*)d_in[0];
    const float* W_in    = (const float*)d_in[1];
    const float* conv_w  = (const float*)d_in[2];
    const float* conv_b  = (const float*)d_in[3];
    const float* dt_bias = (const float*)d_in[4];
    const float* A_log   = (const float*)d_in[5];
    const float* D_param = (const float*)d_in[6];
    const float* rms_w   = (const float*)d_in[7];
    const float* W_out   = (const float*)d_in[8];
    float* out = (float*)d_out;

    float* ws = (float*)d_ws;
    float* dec  = ws;                                      // [32][8] f32
    float* dtb  = dec + 256;                               // [1024][16] f32
    float* psum = dtb + (size_t)BL * 16;                   // [1024][16] f32
    unsigned* flags = (unsigned*)(psum + (size_t)BL * 16); // [256] u32
    unsigned short* u_bf  = (unsigned short*)(flags + 256);            // [1024][512]
    unsigned short* Wt1   = u_bf + (size_t)BL * D_MODEL;               // [2304][512]
    unsigned short* Wt2   = Wt1 + (size_t)NPAD1 * D_MODEL;             // [512][1024] (rms folded)
    unsigned short* xbc   = Wt2 + (size_t)D_MODEL * D_INNER;           // [1024][1152]
    unsigned short* z_bf  = xbc + (size_t)BL * CONV_DIM;               // [1024][1024]
    unsigned short* yz_bf = z_bf + (size_t)BL * D_INNER;               // [1024][1024]
    unsigned short* Zbuf  = yz_bf + (size_t)BL * D_INNER;              // [32][8][64][64] bf16

    // 0) weight transposes (+rms fold) + u -> bf16 + flag reset
    prep_kernel<<<672, 256, 0, stream>>>(W_in, W_out, rms_w, u, Wt1, Wt2, u_bf, flags);

    // 1) in_proj (split epilogue: z bf16 | xBC bf16 | dt f32)
    gemm_in<<<dim3(NPAD1 / 64, BL / 64), 256, 0, stream>>>(
        u_bf, Wt1, z_bf, xbc, dtb);

    // 2) fused SSD (diag + inter-chunk via flags) + gate + psum
    ssd_fused<<<B_SZ * NCH * NHEADS, 256, 0, stream>>>(
        xbc, dtb, z_bf, conv_w, conv_b, dt_bias, A_log, D_param,
        yz_bf, psum, Zbuf, dec, flags);

    // 3) out_proj with RMS row-scale epilogue
    gemm_out<<<dim3(D_MODEL / 64, BL / 32), 256, 0, stream>>>(
        yz_bf, Wt2, psum, out);
}

// Round 17
// 46.204 us; speedup vs baseline: 1.1901x; 1.1901x over previous
//
#include <hip/hip_runtime.h>
#include <hip/hip_bf16.h>

// ---------------- constants ----------------
#define B_SZ 2
#define L_SZ 512
#define D_MODEL 512
#define D_INNER 1024
#define HEAD_DIM 64
#define NHEADS 16
#define D_STATE 64
#define D_CONV 3
#define CONV_DIM 1152            // D_INNER + 2*D_STATE
#define D_IN_PROJ 2192           // 2*D_INNER + 2*D_STATE + NHEADS
#define BL (B_SZ * L_SZ)         // 1024
#define RMS_EPS 1e-5f
#define QC 64                    // SSD chunk length
#define NCH 8                    // chunks per batch
#define NPAD1 2304               // W_in^T padded rows
#define PB 72                    // bf16 LDS pitch

typedef __attribute__((ext_vector_type(8))) short short8t;
typedef __attribute__((ext_vector_type(8))) unsigned short ushort8t;
typedef __attribute__((ext_vector_type(4))) unsigned short ushort4t;
typedef __attribute__((ext_vector_type(4))) float f32x4;

__device__ __forceinline__ unsigned short f2bf(float f) {
    unsigned u = __float_as_uint(f);
    u += 0x7fff + ((u >> 16) & 1);          // RNE
    return (unsigned short)(u >> 16);
}
__device__ __forceinline__ float bf2f(unsigned short u) {
    return __uint_as_float(((unsigned)u) << 16);
}

__device__ __forceinline__ void gload_lds16(const void* g, void* lds) {
    __builtin_amdgcn_global_load_lds(
        (const __attribute__((address_space(1))) unsigned int*)g,
        (__attribute__((address_space(3))) unsigned int*)lds, 16, 0, 0);
}

// ---------------- prep: W transposes (+rms fold on W_out) + u -> bf16 ----------------
__device__ __forceinline__ void transpose_tile_bf16(const float* __restrict__ src,
                                                    const float* __restrict__ scale,
                                                    unsigned short* __restrict__ dst,
                                                    int K, int Nin, int tile, int ntn) {
    __shared__ float T[64][65];
    int tid = threadIdx.x;
    int nt = tile % ntn, kt = tile / ntn;
    int n0 = nt * 64, k0 = kt * 64;
#pragma unroll
    for (int rr = 0; rr < 4; ++rr) {
        int k = k0 + (tid >> 4) + rr * 16;
        float sc = scale ? scale[k] : 1.f;
        int nn = (tid & 15) * 4;
#pragma unroll
        for (int q = 0; q < 4; ++q) {
            int n = n0 + nn + q;
            T[(tid >> 4) + rr * 16][nn + q] = (n < Nin) ? src[(size_t)k * Nin + n] * sc : 0.f;
        }
    }
    __syncthreads();
    int nn2 = tid >> 2, kc = tid & 3;
    unsigned short ov[16];
#pragma unroll
    for (int j = 0; j < 16; ++j) ov[j] = f2bf(T[kc * 16 + j][nn2]);
    unsigned short* p = dst + (size_t)(n0 + nn2) * K + k0 + kc * 16;
    *(ushort8t*)p = *(ushort8t*)&ov[0];
    *(ushort8t*)(p + 8) = *(ushort8t*)&ov[8];
}

__global__ __launch_bounds__(256) void prep_kernel(const float* __restrict__ W_in,
                                                   const float* __restrict__ W_out,
                                                   const float* __restrict__ rms_w,
                                                   const float* __restrict__ u,
                                                   unsigned short* __restrict__ Wt1,
                                                   unsigned short* __restrict__ Wt2,
                                                   unsigned short* __restrict__ u_bf) {
    int bid = blockIdx.x;
    if (bid < 288) {
        transpose_tile_bf16(W_in, nullptr, Wt1, D_MODEL, D_IN_PROJ, bid, 36);
    } else if (bid < 416) {
        transpose_tile_bf16(W_out, rms_w, Wt2, D_INNER, D_MODEL, bid - 288, 8);
    } else {
        int i = ((bid - 416) * 256 + threadIdx.x) * 8;
        float4 v0 = *(const float4*)(u + i);
        float4 v1 = *(const float4*)(u + i + 4);
        unsigned short ov[8] = {f2bf(v0.x), f2bf(v0.y), f2bf(v0.z), f2bf(v0.w),
                                f2bf(v1.x), f2bf(v1.y), f2bf(v1.z), f2bf(v1.w)};
        *(ushort8t*)(u_bf + i) = *(ushort8t*)&ov[0];
    }
}

// ---------------- in_proj GEMM 64x64 + split epilogue (all-bf16 outputs) ----------------
// z cols -> z_bf [1024][1024]; xBC cols -> xbc [1024][1152]; dt cols -> f32 dtb.
__global__ __launch_bounds__(256) void gemm_in(const unsigned short* __restrict__ A,
                                               const unsigned short* __restrict__ Bt,
                                               unsigned short* __restrict__ z_bf,
                                               unsigned short* __restrict__ xbc,
                                               float* __restrict__ dtb) {
    const int K = D_MODEL;
    __shared__ char sm[49152];
    int tid = threadIdx.x;
    int w = tid >> 6, l = tid & 63;
    int m0 = blockIdx.y * 64, n0 = blockIdx.x * 64;
    int wm = w >> 1, wn = w & 1;

    f32x4 acc[2][2];
#pragma unroll
    for (int i = 0; i < 2; ++i)
#pragma unroll
        for (int j = 0; j < 2; ++j) acc[i][j] = (f32x4){0.f, 0.f, 0.f, 0.f};

    auto stage = [&](const unsigned short* src, int row0, int k0, char* dst) {
#pragma unroll
        for (int p = 0; p < 2; ++p) {
            int c = w * 2 + p;
            int row = c * 8 + (l >> 3);
            int scb = ((l & 7) << 4) ^ ((row & 7) << 4);
            gload_lds16(src + (size_t)(row0 + row) * K + k0 + (scb >> 1), dst + c * 1024);
        }
    };

    const int nkt = K / 64;   // 8
    stage(A, m0, 0, sm);
    stage(Bt, n0, 0, sm + 8192);
    stage(A, m0, 64, sm + 16384);
    stage(Bt, n0, 64, sm + 16384 + 8192);

    for (int kt = 0; kt < nkt; ++kt) {
        if (kt + 2 < nkt) {
            char* d = sm + ((kt + 2) % 3) * 16384;
            stage(A, m0, (kt + 2) * 64, d);
            stage(Bt, n0, (kt + 2) * 64, d + 8192);
        }
        int inflight = nkt - 1 - kt;
        if (inflight >= 2)      asm volatile("s_waitcnt vmcnt(8)" ::: "memory");
        else if (inflight == 1) asm volatile("s_waitcnt vmcnt(4)" ::: "memory");
        else                    asm volatile("s_waitcnt vmcnt(0)" ::: "memory");
        __builtin_amdgcn_s_barrier();

        const char* Ab = sm + (kt % 3) * 16384;
        const char* Bb = Ab + 8192;
#pragma unroll
        for (int kk = 0; kk < 2; ++kk) {
            short8t af[2], bf[2];
#pragma unroll
            for (int i = 0; i < 2; ++i) {
                int r = wm * 32 + i * 16 + (l & 15);
                int cb = (kk * 64 + (l >> 4) * 16) ^ ((r & 7) << 4);
                af[i] = *(const short8t*)(Ab + r * 128 + cb);
            }
#pragma unroll
            for (int j = 0; j < 2; ++j) {
                int r = wn * 32 + j * 16 + (l & 15);
                int cb = (kk * 64 + (l >> 4) * 16) ^ ((r & 7) << 4);
                bf[j] = *(const short8t*)(Bb + r * 128 + cb);
            }
#pragma unroll
            for (int i = 0; i < 2; ++i)
#pragma unroll
                for (int j = 0; j < 2; ++j)
                    acc[i][j] = __builtin_amdgcn_mfma_f32_16x16x32_bf16(af[i], bf[j], acc[i][j], 0, 0, 0);
        }
        __builtin_amdgcn_s_barrier();
    }

#pragma unroll
    for (int i = 0; i < 2; ++i)
#pragma unroll
        for (int j = 0; j < 2; ++j) {
            int row = m0 + wm * 32 + i * 16 + (l >> 4) * 4;
            int col = n0 + wn * 32 + j * 16 + (l & 15);
#pragma unroll
            for (int r = 0; r < 4; ++r) {
                float v = acc[i][j][r];
                int rr = row + r;
                if (col < D_INNER) {
                    z_bf[(size_t)rr * D_INNER + col] = f2bf(v);
                } else if (col < D_INNER + CONV_DIM) {
                    xbc[(size_t)rr * CONV_DIM + (col - D_INNER)] = f2bf(v);
                } else if (col < D_IN_PROJ) {
                    dtb[(size_t)rr * 16 + (col - D_INNER - CONV_DIM)] = v;
                }
            }
        }
}

// conv+SiLU of 4 channels from compact bf16 xbc; gl = seq position (causal clamp)
__device__ __forceinline__ float4 conv4b(const unsigned short* __restrict__ xrow,
                                         int gl, int ch,
                                         const float* __restrict__ conv_w,
                                         const float* __restrict__ conv_b) {
    ushort4t u2 = *(const ushort4t*)(xrow + ch);
    ushort4t u1 = {0, 0, 0, 0}, u0 = {0, 0, 0, 0};
    if (gl >= 1) u1 = *(const ushort4t*)(xrow + ch - CONV_DIM);
    if (gl >= 2) u0 = *(const ushort4t*)(xrow + ch - 2 * CONV_DIM);
    float4 o;
    float a;
    a = conv_b[ch+0] + conv_w[(ch+0)*3]*bf2f(u0[0]) + conv_w[(ch+0)*3+1]*bf2f(u1[0]) + conv_w[(ch+0)*3+2]*bf2f(u2[0]);
    o.x = a / (1.f + __expf(-a));
    a = conv_b[ch+1] + conv_w[(ch+1)*3]*bf2f(u0[1]) + conv_w[(ch+1)*3+1]*bf2f(u1[1]) + conv_w[(ch+1)*3+2]*bf2f(u2[1]);
    o.y = a / (1.f + __expf(-a));
    a = conv_b[ch+2] + conv_w[(ch+2)*3]*bf2f(u0[2]) + conv_w[(ch+2)*3+1]*bf2f(u1[2]) + conv_w[(ch+2)*3+2]*bf2f(u2[2]);
    o.z = a / (1.f + __expf(-a));
    a = conv_b[ch+3] + conv_w[(ch+3)*3]*bf2f(u0[3]) + conv_w[(ch+3)*3+1]*bf2f(u1[3]) + conv_w[(ch+3)*3+2]*bf2f(u2[3]);
    o.w = a / (1.f + __expf(-a));
    return o;
}

__device__ __forceinline__ float silu(float z) { return z / (1.f + __expf(-z)); }

// ---------------- SSD pass A (conv fused; c==0 rows finalized: gate+psum+yz) ----------------
__global__ __launch_bounds__(256) void ssd_passA(const unsigned short* __restrict__ xbc,
                                                 const float* __restrict__ dtb,
                                                 const unsigned short* __restrict__ z_bf,
                                                 const float* __restrict__ conv_w,
                                                 const float* __restrict__ conv_b,
                                                 const float* __restrict__ dt_bias,
                                                 const float* __restrict__ A_log,
                                                 const float* __restrict__ D_param,
                                                 unsigned short* __restrict__ y_bf,
                                                 unsigned short* __restrict__ yz_bf,
                                                 float* __restrict__ psum,
                                                 unsigned short* __restrict__ Zbuf,
                                                 float* __restrict__ Ebuf) {
    int blk = blockIdx.x;          // b*128 + c*16 + h
    int h = blk & 15;
    int c = (blk >> 4) & 7;
    int b = blk >> 7;
    int tid = threadIdx.x;

    __shared__ __align__(16) unsigned short Cs_bf[QC][PB];   // C[t][n]; reused as P[t][s]
    __shared__ __align__(16) unsigned short Bs_bf[QC][PB];   // B[s][n]
    __shared__ __align__(16) unsigned short XDT_bf[QC][PB];  // XD^T[p][t^f8(p)]
    __shared__ __align__(16) unsigned short BTw_bf[QC][PB];  // (w·B)^T[n][t^f8(n)]
    __shared__ float csh[QC], dts[QC], wh[QC];
    __shared__ float sq_lds[QC][2];
#define PS_bf Cs_bf

    int bl0 = b * L_SZ + c * QC;

    if (tid < 64) {
        int t = tid;
        float draw = dtb[(size_t)(bl0 + t) * 16 + h];
        float dtv = draw + dt_bias[h];
        dtv = (dtv > 20.f) ? dtv : log1pf(expf(dtv));
        float A = -expf(A_log[h]);
        float cs = A * dtv;
#pragma unroll
        for (int off = 1; off < 64; off <<= 1) {
            float tmp = __shfl_up(cs, off);
            if (t >= off) cs += tmp;
        }
        float cs63 = __shfl(cs, 63);
        dts[t] = dtv;
        csh[t] = cs;
        wh[t] = __expf(cs63 - cs);
        Ebuf[(((size_t)(b * NHEADS + h) * NCH) + c) * QC + t] = __expf(cs);
    }

    int row16 = tid >> 4;
    int col4 = (tid & 15) * 4;
#pragma unroll
    for (int r = 0; r < 4; ++r) {
        int t = r * 16 + row16;
        int gl = c * QC + t;
        const unsigned short* xrow = xbc + (size_t)(bl0 + t) * CONV_DIM;
        float4 Bv = conv4b(xrow, gl, D_INNER + col4, conv_w, conv_b);
        float4 Cv = conv4b(xrow, gl, D_INNER + D_STATE + col4, conv_w, conv_b);
        ushort4t bq = {f2bf(Bv.x), f2bf(Bv.y), f2bf(Bv.z), f2bf(Bv.w)};
        ushort4t cq = {f2bf(Cv.x), f2bf(Cv.y), f2bf(Cv.z), f2bf(Cv.w)};
        *(ushort4t*)&Bs_bf[t][col4] = bq;
        *(ushort4t*)&Cs_bf[t][col4] = cq;
    }
    __syncthreads();               // sync1

#pragma unroll
    for (int r = 0; r < 4; ++r) {
        int t = r * 16 + row16;
        int gl = c * QC + t;
        const unsigned short* xrow = xbc + (size_t)(bl0 + t) * CONV_DIM;
        float4 xv = conv4b(xrow, gl, h * HEAD_DIM + col4, conv_w, conv_b);
        float d = dts[t], wt = wh[t];
        xv.x *= d; xv.y *= d; xv.z *= d; xv.w *= d;
        ushort4t xq = {f2bf(xv.x), f2bf(xv.y), f2bf(xv.z), f2bf(xv.w)};
        ushort4t bq = *(ushort4t*)&Bs_bf[t][col4];
#pragma unroll
        for (int q = 0; q < 4; ++q) {
            int ch = col4 + q;
            int f8 = ((ch >> 2) & 7) << 3;
            XDT_bf[ch][t ^ f8] = xq[q];
            BTw_bf[ch][t ^ f8] = f2bf(bf2f(bq[q]) * wt);
        }
    }
    __syncthreads();               // sync2

    int l = tid & 63, wv = tid >> 6;
    int wm = wv >> 1, wn = wv & 1;
    int fr = l & 15, fq = l >> 4;

    f32x4 g[2][2];
    {   // G = C·B^T via MFMA
#pragma unroll
        for (int i = 0; i < 2; ++i)
#pragma unroll
            for (int j = 0; j < 2; ++j) g[i][j] = (f32x4){0.f, 0.f, 0.f, 0.f};
#pragma unroll
        for (int kk = 0; kk < 2; ++kk) {
            short8t af[2], bb[2];
#pragma unroll
            for (int i = 0; i < 2; ++i)
                af[i] = *(const short8t*)&Cs_bf[wm * 32 + i * 16 + fr][kk * 32 + fq * 8];
#pragma unroll
            for (int j = 0; j < 2; ++j)
                bb[j] = *(const short8t*)&Bs_bf[wn * 32 + j * 16 + fr][kk * 32 + fq * 8];
#pragma unroll
            for (int i = 0; i < 2; ++i)
#pragma unroll
                for (int j = 0; j < 2; ++j)
                    g[i][j] = __builtin_amdgcn_mfma_f32_16x16x32_bf16(af[i], bb[j], g[i][j], 0, 0, 0);
        }
    }
    __syncthreads();               // sync3: Cs free

    {   // mask+decay -> P
#pragma unroll
        for (int i = 0; i < 2; ++i)
#pragma unroll
            for (int j = 0; j < 2; ++j) {
                int s = wn * 32 + j * 16 + fr;
                float css = csh[s];
#pragma unroll
                for (int r = 0; r < 4; ++r) {
                    int t = wm * 32 + i * 16 + fq * 4 + r;
                    float v = (s <= t) ? g[i][j][r] * __expf(csh[t] - css) : 0.f;
                    PS_bf[t][s] = f2bf(v);
                }
            }
    }
    __syncthreads();               // sync4

    {   // Y = P·XD + D·x; c==0: gate+psum+yz_bf, else y_bf
        f32x4 yv[2][2];
#pragma unroll
        for (int i = 0; i < 2; ++i)
#pragma unroll
            for (int j = 0; j < 2; ++j) yv[i][j] = (f32x4){0.f, 0.f, 0.f, 0.f};
#pragma unroll
        for (int kk = 0; kk < 2; ++kk) {
            short8t af[2], bb[2];
            int K0 = kk * 32 + fq * 8;
#pragma unroll
            for (int i = 0; i < 2; ++i)
                af[i] = *(const short8t*)&PS_bf[wm * 32 + i * 16 + fr][K0];
#pragma unroll
            for (int j = 0; j < 2; ++j) {
                int r = wn * 32 + j * 16 + fr;
                bb[j] = *(const short8t*)&XDT_bf[r][K0 ^ (((r >> 2) & 7) << 3)];
            }
#pragma unroll
            for (int i = 0; i < 2; ++i)
#pragma unroll
                for (int j = 0; j < 2; ++j)
                    yv[i][j] = __builtin_amdgcn_mfma_f32_16x16x32_bf16(af[i], bb[j], yv[i][j], 0, 0, 0);
        }
        float Dp = D_param[h];
        if (c == 0) {
            float sloc[2][4] = {{0.f, 0.f, 0.f, 0.f}, {0.f, 0.f, 0.f, 0.f}};
#pragma unroll
            for (int i = 0; i < 2; ++i)
#pragma unroll
                for (int j = 0; j < 2; ++j) {
                    int p = wn * 32 + j * 16 + fr;
                    int f8 = ((p >> 2) & 7) << 3;
#pragma unroll
                    for (int r = 0; r < 4; ++r) {
                        int t = wm * 32 + i * 16 + fq * 4 + r;
                        float xval = bf2f(XDT_bf[p][t ^ f8]);
                        float yval = yv[i][j][r] + (Dp / dts[t]) * xval;
                        float z = bf2f(z_bf[(size_t)(bl0 + t) * D_INNER + h * HEAD_DIM + p]);
                        float yz = yval * silu(z);
                        yz_bf[(size_t)(bl0 + t) * D_INNER + h * HEAD_DIM + p] = f2bf(yz);
                        sloc[i][r] += yz * yz;
                    }
                }
#pragma unroll
            for (int i = 0; i < 2; ++i)
#pragma unroll
                for (int r = 0; r < 4; ++r) {
                    float v = sloc[i][r];
                    v += __shfl_xor(v, 1); v += __shfl_xor(v, 2);
                    v += __shfl_xor(v, 4); v += __shfl_xor(v, 8);
                    if (fr == 0) {
                        int t = wm * 32 + i * 16 + fq * 4 + r;
                        sq_lds[t][wn] = v;
                    }
                }
            __syncthreads();
            if (tid < 64)
                psum[(size_t)(bl0 + tid) * 16 + h] = sq_lds[tid][0] + sq_lds[tid][1];
        } else {
#pragma unroll
            for (int i = 0; i < 2; ++i)
#pragma unroll
                for (int j = 0; j < 2; ++j) {
                    int p = wn * 32 + j * 16 + fr;
                    int f8 = ((p >> 2) & 7) << 3;
#pragma unroll
                    for (int r = 0; r < 4; ++r) {
                        int t = wm * 32 + i * 16 + fq * 4 + r;
                        float xval = bf2f(XDT_bf[p][t ^ f8]);
                        float fct = Dp / dts[t];
                        y_bf[(size_t)(bl0 + t) * D_INNER + h * HEAD_DIM + p] =
                            f2bf(yv[i][j][r] + fct * xval);
                    }
                }
        }
    }

    {   // Z = XD^T·(w·B) -> Zbuf (bf16)
        f32x4 zv[2][2];
#pragma unroll
        for (int i = 0; i < 2; ++i)
#pragma unroll
            for (int j = 0; j < 2; ++j) zv[i][j] = (f32x4){0.f, 0.f, 0.f, 0.f};
#pragma unroll
        for (int kk = 0; kk < 2; ++kk) {
            short8t af[2], bb[2];
            int K0 = kk * 32 + fq * 8;
#pragma unroll
            for (int i = 0; i < 2; ++i) {
                int r = wm * 32 + i * 16 + fr;
                af[i] = *(const short8t*)&XDT_bf[r][K0 ^ (((r >> 2) & 7) << 3)];
            }
#pragma unroll
            for (int j = 0; j < 2; ++j) {
                int r = wn * 32 + j * 16 + fr;
                bb[j] = *(const short8t*)&BTw_bf[r][K0 ^ (((r >> 2) & 7) << 3)];
            }
#pragma unroll
            for (int i = 0; i < 2; ++i)
#pragma unroll
                for (int j = 0; j < 2; ++j)
                    zv[i][j] = __builtin_amdgcn_mfma_f32_16x16x32_bf16(af[i], bb[j], zv[i][j], 0, 0, 0);
        }
        unsigned short* Zr = Zbuf + (((size_t)(b * NHEADS + h) * NCH) + c) * (HEAD_DIM * D_STATE);
#pragma unroll
        for (int i = 0; i < 2; ++i)
#pragma unroll
            for (int j = 0; j < 2; ++j) {
                int n = wn * 32 + j * 16 + fr;
#pragma unroll
                for (int r = 0; r < 4; ++r) {
                    int p = wm * 32 + i * 16 + fq * 4 + r;
                    Zr[p * D_STATE + n] = f2bf(zv[i][j][r]);
                }
            }
    }
#undef PS_bf
}

// ---------------- SSD pass C (finalizes c>=1 rows: +Y_off, gate, psum, yz_bf) ----------------
__global__ __launch_bounds__(256) void ssd_passC(const unsigned short* __restrict__ xbc,
                                                 const unsigned short* __restrict__ z_bf,
                                                 const float* __restrict__ conv_w,
                                                 const float* __restrict__ conv_b,
                                                 const unsigned short* __restrict__ Zbuf,
                                                 const float* __restrict__ Ebuf,
                                                 const unsigned short* __restrict__ y_bf,
                                                 unsigned short* __restrict__ yz_bf,
                                                 float* __restrict__ psum) {
    int blk = blockIdx.x;          // 224 = 16h * 7c * 2b
    int h = blk & 15;
    int q = blk >> 4;
    int c = 1 + (q % 7);
    int b = q / 7;
    int tid = threadIdx.x;

    __shared__ __align__(16) unsigned short Cs_bf[QC][PB];
    __shared__ __align__(16) unsigned short S_bf[QC][PB];
    __shared__ float Eh[QC];
    __shared__ float sq_lds[QC][2];

    int bl0 = b * L_SZ + c * QC;
    const unsigned short* Zb = Zbuf + ((size_t)(b * NHEADS + h) * NCH) * (HEAD_DIM * D_STATE);
    const float* Eb = Ebuf + ((size_t)(b * NHEADS + h) * NCH) * QC;

    {
        int p = tid >> 2, nq = (tid & 3) * 16;
        float S16[16];
#pragma unroll
        for (int qq = 0; qq < 16; ++qq) S16[qq] = 0.f;
        float wgt = 1.f;
        for (int j = c - 1; j >= 0; --j) {
            const unsigned short* Zj = Zb + (size_t)j * (HEAD_DIM * D_STATE) + p * D_STATE + nq;
            ushort8t za = *(const ushort8t*)Zj;
            ushort8t zb2 = *(const ushort8t*)(Zj + 8);
#pragma unroll
            for (int qq = 0; qq < 8; ++qq) {
                S16[qq] += wgt * bf2f(za[qq]);
                S16[8 + qq] += wgt * bf2f(zb2[qq]);
            }
            wgt *= Eb[(size_t)j * QC + 63];
        }
#pragma unroll
        for (int q4 = 0; q4 < 4; ++q4) {
            ushort4t s4 = {f2bf(S16[q4 * 4 + 0]), f2bf(S16[q4 * 4 + 1]),
                           f2bf(S16[q4 * 4 + 2]), f2bf(S16[q4 * 4 + 3])};
            *(ushort4t*)&S_bf[p][nq + q4 * 4] = s4;
        }
    }

    int row16 = tid >> 4, col4 = (tid & 15) * 4;
#pragma unroll
    for (int r = 0; r < 4; ++r) {
        int t = r * 16 + row16;
        int gl = c * QC + t;
        const unsigned short* xrow = xbc + (size_t)(bl0 + t) * CONV_DIM;
        float4 Cv = conv4b(xrow, gl, D_INNER + D_STATE + col4, conv_w, conv_b);
        ushort4t cq = {f2bf(Cv.x), f2bf(Cv.y), f2bf(Cv.z), f2bf(Cv.w)};
        *(ushort4t*)&Cs_bf[t][col4] = cq;
    }
    if (tid < 64)
        Eh[tid] = Ebuf[(((size_t)(b * NHEADS + h) * NCH) + c) * QC + tid];
    __syncthreads();

    int l = tid & 63, wv = tid >> 6;
    int wm = wv >> 1, wn = wv & 1;
    int fr = l & 15, fq = l >> 4;
    f32x4 acc[2][2];
#pragma unroll
    for (int i = 0; i < 2; ++i)
#pragma unroll
        for (int j = 0; j < 2; ++j) acc[i][j] = (f32x4){0.f, 0.f, 0.f, 0.f};
#pragma unroll
    for (int kk = 0; kk < 2; ++kk) {
        short8t af[2], bb[2];
#pragma unroll
        for (int i = 0; i < 2; ++i)
            af[i] = *(const short8t*)&Cs_bf[wm * 32 + i * 16 + fr][kk * 32 + fq * 8];
#pragma unroll
        for (int j = 0; j < 2; ++j)
            bb[j] = *(const short8t*)&S_bf[wn * 32 + j * 16 + fr][kk * 32 + fq * 8];
#pragma unroll
        for (int i = 0; i < 2; ++i)
#pragma unroll
            for (int j = 0; j < 2; ++j)
                acc[i][j] = __builtin_amdgcn_mfma_f32_16x16x32_bf16(af[i], bb[j], acc[i][j], 0, 0, 0);
    }

    float sloc[2][4] = {{0.f, 0.f, 0.f, 0.f}, {0.f, 0.f, 0.f, 0.f}};
#pragma unroll
    for (int i = 0; i < 2; ++i)
#pragma unroll
        for (int j = 0; j < 2; ++j) {
            int p = wn * 32 + j * 16 + fr;
#pragma unroll
            for (int r = 0; r < 4; ++r) {
                int t = wm * 32 + i * 16 + fq * 4 + r;
                size_t idx = (size_t)(bl0 + t) * D_INNER + h * HEAD_DIM + p;
                float yval = bf2f(y_bf[idx]) + Eh[t] * acc[i][j][r];
                float z = bf2f(z_bf[idx]);
                float yz = yval * silu(z);
                yz_bf[idx] = f2bf(yz);
                sloc[i][r] += yz * yz;
            }
        }
#pragma unroll
    for (int i = 0; i < 2; ++i)
#pragma unroll
        for (int r = 0; r < 4; ++r) {
            float v = sloc[i][r];
            v += __shfl_xor(v, 1); v += __shfl_xor(v, 2);
            v += __shfl_xor(v, 4); v += __shfl_xor(v, 8);
            if (fr == 0) {
                int t = wm * 32 + i * 16 + fq * 4 + r;
                sq_lds[t][wn] = v;
            }
        }
    __syncthreads();
    if (tid < 64)
        psum[(size_t)(bl0 + tid) * 16 + h] = sq_lds[tid][0] + sq_lds[tid][1];
}

// ---------------- out_proj GEMM 32x64 + RMS row-scale epilogue ----------------
__global__ __launch_bounds__(256) void gemm_out(const unsigned short* __restrict__ A,
                                                const unsigned short* __restrict__ Bt,
                                                const float* __restrict__ psum,
                                                float* __restrict__ C) {
    const int N = D_MODEL, K = D_INNER;
    __shared__ char sm[36864];
    __shared__ float scl[32];
    int tid = threadIdx.x;
    int w = tid >> 6, l = tid & 63;
    int m0 = blockIdx.y * 32, n0 = blockIdx.x * 64;
    int wm = w >> 1, wn = w & 1;

    f32x4 acc[2];
    acc[0] = (f32x4){0.f, 0.f, 0.f, 0.f};
    acc[1] = (f32x4){0.f, 0.f, 0.f, 0.f};

    auto stageA = [&](int k0, char* dst) {
        int row = w * 8 + (l >> 3);
        int scb = ((l & 7) << 4) ^ ((row & 7) << 4);
        gload_lds16(A + (size_t)(m0 + row) * K + k0 + (scb >> 1), dst + w * 1024);
    };
    auto stageB = [&](int k0, char* dst) {
#pragma unroll
        for (int p = 0; p < 2; ++p) {
            int c = w * 2 + p;
            int row = c * 8 + (l >> 3);
            int scb = ((l & 7) << 4) ^ ((row & 7) << 4);
            gload_lds16(Bt + (size_t)(n0 + row) * K + k0 + (scb >> 1), dst + c * 1024);
        }
    };

    const int nkt = K / 64;   // 16
    stageA(0, sm); stageB(0, sm + 4096);
    stageA(64, sm + 12288); stageB(64, sm + 12288 + 4096);

    for (int kt = 0; kt < nkt; ++kt) {
        if (kt + 2 < nkt) {
            char* d = sm + ((kt + 2) % 3) * 12288;
            stageA((kt + 2) * 64, d);
            stageB((kt + 2) * 64, d + 4096);
        }
        int inflight = nkt - 1 - kt;
        if (inflight >= 2)      asm volatile("s_waitcnt vmcnt(6)" ::: "memory");
        else if (inflight == 1) asm volatile("s_waitcnt vmcnt(3)" ::: "memory");
        else                    asm volatile("s_waitcnt vmcnt(0)" ::: "memory");
        __builtin_amdgcn_s_barrier();

        const char* Ab = sm + (kt % 3) * 12288;
        const char* Bb = Ab + 4096;
#pragma unroll
        for (int kk = 0; kk < 2; ++kk) {
            short8t af;
            {
                int r = wm * 16 + (l & 15);
                int cb = (kk * 64 + (l >> 4) * 16) ^ ((r & 7) << 4);
                af = *(const short8t*)(Ab + r * 128 + cb);
            }
#pragma unroll
            for (int j = 0; j < 2; ++j) {
                int r = wn * 32 + j * 16 + (l & 15);
                int cb = (kk * 64 + (l >> 4) * 16) ^ ((r & 7) << 4);
                short8t bfv = *(const short8t*)(Bb + r * 128 + cb);
                acc[j] = __builtin_amdgcn_mfma_f32_16x16x32_bf16(af, bfv, acc[j], 0, 0, 0);
            }
        }
        __builtin_amdgcn_s_barrier();
    }

    if (tid < 32) {
        const float* pr = psum + (size_t)(m0 + tid) * 16;
        float s = 0.f;
#pragma unroll
        for (int qq = 0; qq < 16; ++qq) s += pr[qq];
        scl[tid] = rsqrtf(s / (float)D_INNER + RMS_EPS);
    }
    __syncthreads();

#pragma unroll
    for (int j = 0; j < 2; ++j) {
        int col = n0 + wn * 32 + j * 16 + (l & 15);
        int rloc = wm * 16 + (l >> 4) * 4;
#pragma unroll
        for (int r = 0; r < 4; ++r)
            C[(size_t)(m0 + rloc + r) * N + col] = acc[j][r] * scl[rloc + r];
    }
}

// ---------------- launch ----------------
extern "C" void kernel_launch(void* const* d_in, const int* in_sizes, int n_in,
                              void* d_out, int out_size, void* d_ws, size_t ws_size,
                              hipStream_t stream) {
    const float* u       = (const float*)d_in[0];
    const float* W_in    = (const float*)d_in[1];
    const float* conv_w  = (const float*)d_in[2];
    const float* conv_b  = (const float*)d_in[3];
    const float* dt_bias = (const float*)d_in[4];
    const float* A_log   = (const float*)d_in[5];
    const float* D_param = (const float*)d_in[6];
    const float* rms_w   = (const float*)d_in[7];
    const float* W_out   = (const float*)d_in[8];
    float* out = (float*)d_out;

    float* ws = (float*)d_ws;
    float* Ebuf = ws;                                      // [32*8*64] f32
    float* dtb  = Ebuf + (size_t)32 * NCH * QC;            // [1024][16] f32
    float* psum = dtb + (size_t)BL * 16;                   // [1024][16] f32
    unsigned short* u_bf  = (unsigned short*)(psum + (size_t)BL * 16); // [1024][512]
    unsigned short* Wt1   = u_bf + (size_t)BL * D_MODEL;               // [2304][512]
    unsigned short* Wt2   = Wt1 + (size_t)NPAD1 * D_MODEL;             // [512][1024] (rms folded)
    unsigned short* xbc   = Wt2 + (size_t)D_MODEL * D_INNER;           // [1024][1152]
    unsigned short* z_bf  = xbc + (size_t)BL * CONV_DIM;               // [1024][1024]
    unsigned short* y_bf  = z_bf + (size_t)BL * D_INNER;               // [1024][1024]
    unsigned short* yz_bf = y_bf + (size_t)BL * D_INNER;               // [1024][1024]
    unsigned short* Zbuf  = yz_bf + (size_t)BL * D_INNER;              // [32][8][64][64] bf16

    // 0) weight transposes (+rms fold) + u -> bf16
    prep_kernel<<<672, 256, 0, stream>>>(W_in, W_out, rms_w, u, Wt1, Wt2, u_bf);

    // 1) in_proj (split epilogue: z bf16 | xBC bf16 | dt f32)
    gemm_in<<<dim3(NPAD1 / 64, BL / 64), 256, 0, stream>>>(
        u_bf, Wt1, z_bf, xbc, dtb);

    // 2) SSD; c==0 rows finalized in passA, c>=1 in passC (gate+psum+yz fused)
    ssd_passA<<<B_SZ * NCH * NHEADS, 256, 0, stream>>>(
        xbc, dtb, z_bf, conv_w, conv_b, dt_bias, A_log, D_param,
        y_bf, yz_bf, psum, Zbuf, Ebuf);
    ssd_passC<<<224, 256, 0, stream>>>(
        xbc, z_bf, conv_w, conv_b, Zbuf, Ebuf, y_bf, yz_bf, psum);

    // 3) out_proj with RMS row-scale epilogue
    gemm_out<<<dim3(D_MODEL / 64, BL / 32), 256, 0, stream>>>(
        yz_bf, Wt2, psum, out);
}